// Round 4
// baseline (244.551 us; speedup 1.0000x reference)
//
#include <hip/hip_runtime.h>

// MyLSTM: 2-layer LSTM (input=3, hidden=4) + MLP head (4->4 tanh -> 1), B=4096, T=1024.
//
// R12 = R11 (147.5 us kernel) + three zero-math-change latency cuts. Model (from R9:
// issue cut -> wall flat; R11: chain cut -> wall -46 cyc/step): wall = serial dep chain
// of one cell wave's step (~19 ops incl 4 dependent trans), ~346 cyc/step. Remaining
// above-floor items removed here:
//  1. CROSS-CHUNK PREPASS PIPELINING (A and B): compute chunk c+1's xg[]/xb[] (16x
//     ds_read_b128 + FMA folds) INSIDE chunk c's body — the body stalls ~60% on chain
//     deps, so the prepass rides free issue slots. Removes ~90-150 cyc/chunk of exposed
//     poll+ds+FMA latency per cell wave. Chunk loop unrolled x2 for xg/xb double-buffer
//     (static indexing, no scratch).
//  2. s_setprio: B=2 (downstream laggard, its chain IS the wall), A=1, C=0. Removes
//     issue-arbitration jitter (+1-4 cyc/chain-hop x ~19 hops) from the critical wave.
//  3. EARLY ring0 credit release: B releases free0[slot] at iteration START (its LDS
//     reads of that chunk completed in the PREVIOUS iteration's prepass; per-wave LDS
//     pipe is in-order, so the flag ds_write cannot pass the reads). A gets more slack.
// Cell math byte-identical per chain to R8-R11 (same ops, same order) => absmax must
// stay exactly 0.001953125. Ring/flag protocol unchanged otherwise: monotonic chunk
// counters, __threadfence_block before done-flags, s_sleep polling.

#define T_STEPS 1024
#define BATCH   4096
#define CHUNK   16
#define NCHUNK  (T_STEPS / CHUNK)
#define RDEPTH  4   // ring depth in chunks (power of 2)

__device__ __forceinline__ float fast_exp2(float x) {
#if __has_builtin(__builtin_amdgcn_exp2f)
    return __builtin_amdgcn_exp2f(x);
#else
    return exp2f(x);
#endif
}

__device__ __forceinline__ float fast_rcp(float x) {
#if __has_builtin(__builtin_amdgcn_rcpf)
    return __builtin_amdgcn_rcpf(x);
#else
    return 1.0f / x;
#endif
}

// tanh(x) = 2*sigmoid(2x) - 1 = 2/(1+exp2(-2.885390x)) - 1
__device__ __forceinline__ float fast_tanh(float x) {
    return 2.0f * fast_rcp(1.0f + fast_exp2(-2.88539008f * x)) - 1.0f;
}

template <int CTRL>
__device__ __forceinline__ float dpp_mov(float v) {
    int i = __builtin_bit_cast(int, v);
    i = __builtin_amdgcn_mov_dpp(i, CTRL, 0xF, 0xF, true);
    return __builtin_bit_cast(float, i);
}

#define DPP_QB0         0x00   // quad_perm [0,0,0,0] -> i gate
#define DPP_QB1         0x55   // quad_perm [1,1,1,1] -> f gate
#define DPP_QB2         0xAA   // quad_perm [2,2,2,2] -> g gate
#define DPP_QB3         0xFF   // quad_perm [3,3,3,3] -> o gate
#define DPP_ROR8        0x128  // l^8  -> u^2 (on quad-uniform data)
#define DPP_MIRROR      0x140  // l^15 -> u^3 (on quad-uniform data)
#define DPP_HALF_MIRROR 0x141  // l^7  -> u^1 (on quad-uniform data)
#define DPP_QSWAP2      0x4E   // quad_perm [2,3,0,1] -> u^2 within quad
#define DPP_QSWAP1      0xB1   // quad_perm [1,0,3,2] -> u^1 within quad

__global__ __launch_bounds__(768) void lstm_r12_kernel(
    const float* __restrict__ x,
    const float* __restrict__ W_ih0, const float* __restrict__ W_hh0,
    const float* __restrict__ b_ih0, const float* __restrict__ b_hh0,
    const float* __restrict__ W_ih1, const float* __restrict__ W_hh1,
    const float* __restrict__ b_ih1, const float* __restrict__ b_hh1,
    const float* __restrict__ W1, const float* __restrict__ b1,
    const float* __restrict__ W2, const float* __restrict__ b2,
    float* __restrict__ out)
{
    // x stage: [pair][slot][ch*17 + step] (A-private, self-ordered; +17 pad)
    __shared__ float4 xstage[4][2][68];
    // h0 ring A->B: [pair][slot][step][chain], plain-order h[4] per chain (16 KB)
    __shared__ float4 ring0[4][RDEPTH][CHUNK][4];
    // h1 ring B->C: same layout (16 KB)
    __shared__ float4 ring1[4][RDEPTH][CHUNK][4];
    // monotonic chunk counters (value c+1 = chunk c produced / freed)
    __shared__ int done0[4][RDEPTH];
    __shared__ int free0[4][RDEPTH];
    __shared__ int done1[4][RDEPTH];
    __shared__ int free1[4][RDEPTH];

    const int tid  = threadIdx.x;
    const int wave = tid >> 6;
    const int stg  = wave >> 2;         // 0 = L0 producer, 1 = L1 mid, 2 = head consumer
    const int pr   = wave & 3;          // pair index: A/B/C waves with same pr share rings
    const int lane = tid & 63;
    const int idx  = lane & 15;         // lane within 16-lane chain group (also step-slot)
    const int rho  = lane & 3;          // role: 0=i,1=f,2=g,3=o
    const int u    = (lane >> 2) & 3;   // hidden unit
    const int r    = rho * 4 + u;       // gate row in 16-row weight matrices
    const int ch   = lane >> 4;         // chain within pair
    const int batch = blockIdx.x * 16 + pr * 4 + ch;

    // init flags, one barrier total (outside hot loop)
    if (tid < 4 * RDEPTH) {
        done0[tid >> 2][tid & 3] = 0;
        free0[tid >> 2][tid & 3] = 0;
        done1[tid >> 2][tid & 3] = 0;
        free1[tid >> 2][tid & 3] = 0;
    }
    __syncthreads();

    // Per-lane activation constants: role g (rho==2) uses tanh = 2*sigma(2x)-1.
    const float am = (rho == 2) ? -2.88539008f : -1.44269504f;
    const float aa = (rho == 2) ? 2.0f : 1.0f;
    const float ab = (rho == 2) ? -1.0f : 0.0f;

    if (stg == 0) {
        // ======================= stage A: layer 0 producer =======================
        __builtin_amdgcn_s_setprio(1);
        const float wx0 = W_ih0[r * 3 + 0];
        const float wx1 = W_ih0[r * 3 + 1];
        const float wx2 = W_ih0[r * 3 + 2];
        const float bias0 = b_ih0[r] + b_hh0[r];
        float wh0[4];
#pragma unroll
        for (int k = 0; k < 4; ++k) wh0[k] = W_hh0[r * 4 + (u ^ k)];   // xor order

        float h0 = 0.f, c0 = 0.f, h0b = 0.f, h0c = 0.f, h0d = 0.f;

        const float* xrow = x + (size_t)batch * T_STEPS * 3;
        // prologue: stage chunk 0 into x-slot 0; q <- chunk 1; prepass xg for chunk 0
        const float* p0 = xrow + idx * 3;
        xstage[pr][0][ch * 17 + idx] = make_float4(p0[0], p0[1], p0[2], 0.f);
        const float* p1 = xrow + 48 + idx * 3;
        float q0 = p1[0], q1 = p1[1], q2 = p1[2];

        float xgA[CHUNK], xgB[CHUNK];
        {
            const float4* xs = &xstage[pr][0][ch * 17];   // in-order LDS: sees own writes
#pragma unroll
            for (int tt = 0; tt < CHUNK; ++tt) {
                float4 xv = xs[tt];
                xgA[tt] = bias0 + wx0 * xv.x + wx1 * xv.y + wx2 * xv.z;
            }
        }

        volatile int* ff = &free0[pr][0];

        auto a_chunk = [&](int c, float (&xg_cur)[CHUNK], float (&xg_nxt)[CHUNK]) {
            const int s = c & (RDEPTH - 1);
            // stage chunk c+1 (q holds its data), then issue q loads for chunk c+2
            if (c < NCHUNK - 1)
                xstage[pr][(c + 1) & 1][ch * 17 + idx] = make_float4(q0, q1, q2, 0.f);
            if (c < NCHUNK - 2) {
                const float* p = xrow + (c + 2) * 48 + idx * 3;
                q0 = p[0]; q1 = p[1]; q2 = p[2];
            }

            // ---- body: pure-register recurrence (chain-bound; stalls host the
            //      prepass-next ds_reads/FMAs below via the scheduler) ----
            float hs0[CHUNK];
#pragma unroll
            for (int tt = 0; tt < CHUNK; ++tt) {
                float pre0 = xg_cur[tt]
                           + wh0[0] * h0 + wh0[1] * h0b + wh0[2] * h0c + wh0[3] * h0d;
                float a0 = aa * fast_rcp(1.0f + fast_exp2(am * pre0)) + ab;
                float gi = dpp_mov<DPP_QB0>(a0);
                float gf = dpp_mov<DPP_QB1>(a0);
                float gg = dpp_mov<DPP_QB2>(a0);
                float go = dpp_mov<DPP_QB3>(a0);
                c0 = gf * c0 + gi * gg;
                h0 = go * fast_tanh(c0);
                h0b = dpp_mov<DPP_HALF_MIRROR>(h0);
                h0c = dpp_mov<DPP_ROR8>(h0);
                h0d = dpp_mov<DPP_MIRROR>(h0);
                hs0[tt] = h0;
            }

            // ---- prepass for chunk c+1 (reads the slot staged above; same-wave
            //      LDS is in-order so the reads see the writes) ----
            if (c < NCHUNK - 1) {
                const float4* xs = &xstage[pr][(c + 1) & 1][ch * 17];
#pragma unroll
                for (int tt = 0; tt < CHUNK; ++tt) {
                    float4 xv = xs[tt];
                    xg_nxt[tt] = bias0 + wx0 * xv.x + wx1 * xv.y + wx2 * xv.z;
                }
            }

            // ---- ring credit (only gates the writes), then batched ring writes ----
            if (c >= RDEPTH) {
                while (ff[s] < c - RDEPTH + 1) { __builtin_amdgcn_s_sleep(1); }
            }
            if (rho == 0) {
                float* rw = &((float*)&ring0[pr][s][0][ch])[u];   // step stride 16 floats
#pragma unroll
                for (int tt = 0; tt < CHUNK; ++tt) rw[tt * 16] = hs0[tt];
            }
            __threadfence_block();
            if (lane == 0) done0[pr][s] = c + 1;
        };

        for (int c = 0; c < NCHUNK; c += 2) {
            a_chunk(c, xgA, xgB);
            a_chunk(c + 1, xgB, xgA);
        }
    } else if (stg == 1) {
        // ==================== stage B: layer 1 (cell only) =======================
        __builtin_amdgcn_s_setprio(2);
        const float bias1 = b_ih1[r] + b_hh1[r];
        float wi1[4], wh1[4];
#pragma unroll
        for (int k = 0; k < 4; ++k) {
            wi1[k] = W_ih1[r * 4 + k];          // PLAIN order (ring h0 is plain)
            wh1[k] = W_hh1[r * 4 + (u ^ k)];    // xor order (register quad)
        }

        float h1 = 0.f, c1 = 0.f, h1b = 0.f, h1c = 0.f, h1d = 0.f;

        volatile int* df = &done0[pr][0];
        volatile int* f1 = &free1[pr][0];

        // prologue: wait for chunk 0, prepass xb for chunk 0
        float xbA[CHUNK], xbB[CHUNK];
        while (df[0] < 1) { __builtin_amdgcn_s_sleep(1); }
        __threadfence_block();
        {
            const float4* rgp = &ring0[pr][0][0][ch];
#pragma unroll
            for (int tt = 0; tt < CHUNK; ++tt) {
                float4 hv = rgp[tt * 4];
                xbA[tt] = bias1 + wi1[0] * hv.x + wi1[1] * hv.y
                                + wi1[2] * hv.z + wi1[3] * hv.w;
            }
        }

        auto b_chunk = [&](int c, float (&xb_cur)[CHUNK], float (&xb_nxt)[CHUNK]) {
            const int s = c & (RDEPTH - 1);
            // EARLY release of ring0 slot s: its reads completed in the previous
            // iteration's prepass (in-order per-wave LDS: this flag ds_write cannot
            // pass those ds_reads).
            if (lane == 0) free0[pr][s] = c + 1;

            // done-poll for chunk c+1 (steady-state hit: A runs RDEPTH ahead)
            if (c < NCHUNK - 1) {
                while (df[(c + 1) & (RDEPTH - 1)] < c + 2) { __builtin_amdgcn_s_sleep(1); }
                __threadfence_block();
            }

            // ---- body: pure-register recurrence ----
            float hs1[CHUNK];
#pragma unroll
            for (int tt = 0; tt < CHUNK; ++tt) {
                float pre1 = xb_cur[tt]
                           + wh1[0] * h1 + wh1[1] * h1b + wh1[2] * h1c + wh1[3] * h1d;
                float a1 = aa * fast_rcp(1.0f + fast_exp2(am * pre1)) + ab;
                float gi1 = dpp_mov<DPP_QB0>(a1);
                float gf1 = dpp_mov<DPP_QB1>(a1);
                float gg1 = dpp_mov<DPP_QB2>(a1);
                float go1 = dpp_mov<DPP_QB3>(a1);
                c1 = gf1 * c1 + gi1 * gg1;
                h1 = go1 * fast_tanh(c1);
                h1b = dpp_mov<DPP_HALF_MIRROR>(h1);
                h1c = dpp_mov<DPP_ROR8>(h1);
                h1d = dpp_mov<DPP_MIRROR>(h1);
                hs1[tt] = h1;
            }

            // ---- prepass for chunk c+1 (rides the body's chain-stall slots) ----
            if (c < NCHUNK - 1) {
                const float4* rgp = &ring0[pr][(c + 1) & (RDEPTH - 1)][0][ch];
#pragma unroll
                for (int tt = 0; tt < CHUNK; ++tt) {
                    float4 hv = rgp[tt * 4];
                    xb_nxt[tt] = bias1 + wi1[0] * hv.x + wi1[1] * hv.y
                                       + wi1[2] * hv.z + wi1[3] * hv.w;
                }
            }

            // ---- ring1 credit (gates only the writes), batched writes, publish ----
            if (c >= RDEPTH) {
                while (f1[s] < c - RDEPTH + 1) { __builtin_amdgcn_s_sleep(1); }
            }
            if (rho == 0) {
                float* rw = &((float*)&ring1[pr][s][0][ch])[u];
#pragma unroll
                for (int tt = 0; tt < CHUNK; ++tt) rw[tt * 16] = hs1[tt];
            }
            __threadfence_block();
            if (lane == 0) done1[pr][s] = c + 1;
        };

        for (int c = 0; c < NCHUNK; c += 2) {
            b_chunk(c, xbA, xbB);
            b_chunk(c + 1, xbB, xbA);
        }
    } else {
        // =================== stage C: MLP head consumer ==========================
        // Zero-redundancy layout: lane = cch*16 + sb*4 + cu handles (chain cch,
        // step it*4+sb, unit cu) -> 4 timesteps per iteration across 64 lanes.
        const int cu  = lane & 3;           // hidden unit
        const int sb  = (lane >> 2) & 3;    // step sub-slot
        const int cch = lane >> 4;          // chain within pair
        const int cbatch = blockIdx.x * 16 + pr * 4 + cch;

        float w1r[4];
#pragma unroll
        for (int k = 0; k < 4; ++k) w1r[k] = W1[cu * 4 + k];   // plain order
        const float b1u = b1[cu];
        const float w2u = W2[cu];
        const float b2v = b2[0];
        float* op = out + (size_t)cbatch * T_STEPS;

        volatile int* d1 = &done1[pr][0];

        for (int c = 0; c < NCHUNK; ++c) {
            const int s = c & (RDEPTH - 1);
            while (d1[s] < c + 1) { __builtin_amdgcn_s_sleep(1); }
            __threadfence_block();

            // lane reads h1[chain cch][t = it*4+sb] as one float4 (quad-broadcast,
            // 2-way bank aliasing = free); it*16 float4s = it*256 B imm offset
            const float4* rg = &ring1[pr][s][sb][cch];
            float yq[4];
#pragma unroll
            for (int it = 0; it < 4; ++it) {
                float4 h = rg[it * 16];
                float zp = b1u + w1r[0] * h.x + w1r[1] * h.y
                               + w1r[2] * h.z + w1r[3] * h.w;
                float z  = fast_tanh(zp);
                float yv = w2u * z;
                // sum over the 4 units of the quad: (u + u^2) + (u^1 + u^3) + b2
                float t1 = yv + dpp_mov<DPP_QSWAP2>(yv);
                yq[it]   = t1 + dpp_mov<DPP_QSWAP1>(t1) + b2v;
            }
            // release ring1 slot (all reads consumed above; values live in yq regs)
            if (lane == 0) free1[pr][s] = c + 1;

            // store: 16 active lanes (cch, sb), 4 consecutive floats per chain per it
            if (cu == 0) {
#pragma unroll
                for (int it = 0; it < 4; ++it)
                    op[c * CHUNK + it * 4 + sb] = yq[it];
            }
        }
    }
}

extern "C" void kernel_launch(void* const* d_in, const int* in_sizes, int n_in,
                              void* d_out, int out_size, void* d_ws, size_t ws_size,
                              hipStream_t stream) {
    const float* x     = (const float*)d_in[0];
    const float* W_ih0 = (const float*)d_in[1];
    const float* W_hh0 = (const float*)d_in[2];
    const float* b_ih0 = (const float*)d_in[3];
    const float* b_hh0 = (const float*)d_in[4];
    const float* W_ih1 = (const float*)d_in[5];
    const float* W_hh1 = (const float*)d_in[6];
    const float* b_ih1 = (const float*)d_in[7];
    const float* b_hh1 = (const float*)d_in[8];
    const float* W1    = (const float*)d_in[9];
    const float* b1    = (const float*)d_in[10];
    const float* W2    = (const float*)d_in[11];
    const float* b2    = (const float*)d_in[12];
    float* out = (float*)d_out;

    dim3 grid(BATCH / 16);   // 256 blocks = 1 per CU, 16 chains each
    dim3 block(768);         // 12 waves: 4x A (L0) + 4x B (L1) + 4x C (head);
                             // w%4 round-robin -> each SIMD gets one A, one B, one C
    lstm_r12_kernel<<<grid, block, 0, stream>>>(
        x, W_ih0, W_hh0, b_ih0, b_hh0, W_ih1, W_hh1, b_ih1, b_hh1,
        W1, b1, W2, b2, out);
}

// Round 5
// 239.988 us; speedup vs baseline: 1.0190x; 1.0190x over previous
//
#include <hip/hip_runtime.h>

// MyLSTM: 2-layer LSTM (input=3, hidden=4) + MLP head (4->4 tanh -> 1), B=4096, T=1024.
//
// R13 = R11 (147.5 us, best) with ONE change: the wave->(stage,pair) mapping is
// permuted so each SIMD hosts TWO INDEPENDENT SAME-STAGE cell waves (+ one C wave),
// instead of R11's one-A+one-B+one-C (coupled through the ring: B waits on A).
//
// Model (R9: -20 inst/step in B -> wall flat; R11: chain cut -> wall -46 cyc/step;
// R10: software 2-chain interleave in one wave -> WORSE): wall = serial dep chain of
// one cell wave's step (~346 cyc incl 4 dependent transcendentals), which a single
// wave cannot hide. Hardware interleaving of two waves on one SIMD hides it for free:
// when B-pr0 stalls on exp2->rcp, B-pr1 issues. R10 failed because one wave has one
// program counter; two waves have two.
//
// Mapping (w%4 = SIMD round-robin): q=wave&3, d=wave>>2.
//   d<2  -> cell wave: stg = (q>=2), pr = (q&1)*2 + d
//           S0: A-pr0,A-pr1 | S1: A-pr2,A-pr3 | S2: B-pr0,B-pr1 | S3: B-pr2,B-pr3
//   d==2 -> C wave, pr = q (C-pr_k on SIMD k; rings cross SIMDs via CU-shared LDS).
//
// Everything else is VERBATIM R11: same rings, flags, prepass/body/batched-write
// structure, same grid/block. Cell math byte-identical => absmax stays 0.001953125.

#define T_STEPS 1024
#define BATCH   4096
#define CHUNK   16
#define NCHUNK  (T_STEPS / CHUNK)
#define RDEPTH  4   // ring depth in chunks (power of 2)

__device__ __forceinline__ float fast_exp2(float x) {
#if __has_builtin(__builtin_amdgcn_exp2f)
    return __builtin_amdgcn_exp2f(x);
#else
    return exp2f(x);
#endif
}

__device__ __forceinline__ float fast_rcp(float x) {
#if __has_builtin(__builtin_amdgcn_rcpf)
    return __builtin_amdgcn_rcpf(x);
#else
    return 1.0f / x;
#endif
}

// tanh(x) = 2*sigmoid(2x) - 1 = 2/(1+exp2(-2.885390x)) - 1
__device__ __forceinline__ float fast_tanh(float x) {
    return 2.0f * fast_rcp(1.0f + fast_exp2(-2.88539008f * x)) - 1.0f;
}

template <int CTRL>
__device__ __forceinline__ float dpp_mov(float v) {
    int i = __builtin_bit_cast(int, v);
    i = __builtin_amdgcn_mov_dpp(i, CTRL, 0xF, 0xF, true);
    return __builtin_bit_cast(float, i);
}

#define DPP_QB0         0x00   // quad_perm [0,0,0,0] -> i gate
#define DPP_QB1         0x55   // quad_perm [1,1,1,1] -> f gate
#define DPP_QB2         0xAA   // quad_perm [2,2,2,2] -> g gate
#define DPP_QB3         0xFF   // quad_perm [3,3,3,3] -> o gate
#define DPP_ROR8        0x128  // l^8  -> u^2 (on quad-uniform data)
#define DPP_MIRROR      0x140  // l^15 -> u^3 (on quad-uniform data)
#define DPP_HALF_MIRROR 0x141  // l^7  -> u^1 (on quad-uniform data)
#define DPP_QSWAP2      0x4E   // quad_perm [2,3,0,1] -> u^2 within quad
#define DPP_QSWAP1      0xB1   // quad_perm [1,0,3,2] -> u^1 within quad

__global__ __launch_bounds__(768) void lstm_r13_kernel(
    const float* __restrict__ x,
    const float* __restrict__ W_ih0, const float* __restrict__ W_hh0,
    const float* __restrict__ b_ih0, const float* __restrict__ b_hh0,
    const float* __restrict__ W_ih1, const float* __restrict__ W_hh1,
    const float* __restrict__ b_ih1, const float* __restrict__ b_hh1,
    const float* __restrict__ W1, const float* __restrict__ b1,
    const float* __restrict__ W2, const float* __restrict__ b2,
    float* __restrict__ out)
{
    // x stage: [pair][slot][ch*17 + step] (A-private, self-ordered; +17 pad)
    __shared__ float4 xstage[4][2][68];
    // h0 ring A->B: [pair][slot][step][chain], plain-order h[4] per chain (16 KB)
    __shared__ float4 ring0[4][RDEPTH][CHUNK][4];
    // h1 ring B->C: same layout (16 KB)
    __shared__ float4 ring1[4][RDEPTH][CHUNK][4];
    // monotonic chunk counters (value c+1 = chunk c produced / freed)
    __shared__ int done0[4][RDEPTH];
    __shared__ int free0[4][RDEPTH];
    __shared__ int done1[4][RDEPTH];
    __shared__ int free1[4][RDEPTH];

    const int tid  = threadIdx.x;
    const int wave = tid >> 6;
    const int q    = wave & 3;          // SIMD id under w%4 round-robin
    const int d    = wave >> 2;         // 0,1 = cell waves; 2 = head waves
    const int stg  = (d == 2) ? 2 : ((q >= 2) ? 1 : 0);
    const int pr   = (d == 2) ? q : ((q & 1) * 2 + d);
    const int lane = tid & 63;
    const int idx  = lane & 15;         // lane within 16-lane chain group (also step-slot)
    const int rho  = lane & 3;          // role: 0=i,1=f,2=g,3=o
    const int u    = (lane >> 2) & 3;   // hidden unit
    const int r    = rho * 4 + u;       // gate row in 16-row weight matrices
    const int ch   = lane >> 4;         // chain within pair
    const int batch = blockIdx.x * 16 + pr * 4 + ch;

    // init flags, one barrier total (outside hot loop)
    if (tid < 4 * RDEPTH) {
        done0[tid >> 2][tid & 3] = 0;
        free0[tid >> 2][tid & 3] = 0;
        done1[tid >> 2][tid & 3] = 0;
        free1[tid >> 2][tid & 3] = 0;
    }
    __syncthreads();

    // Per-lane activation constants: role g (rho==2) uses tanh = 2*sigma(2x)-1.
    const float am = (rho == 2) ? -2.88539008f : -1.44269504f;
    const float aa = (rho == 2) ? 2.0f : 1.0f;
    const float ab = (rho == 2) ? -1.0f : 0.0f;

    if (stg == 0) {
        // ======================= stage A: layer 0 producer =======================
        const float wx0 = W_ih0[r * 3 + 0];
        const float wx1 = W_ih0[r * 3 + 1];
        const float wx2 = W_ih0[r * 3 + 2];
        const float bias0 = b_ih0[r] + b_hh0[r];
        float wh0[4];
#pragma unroll
        for (int k = 0; k < 4; ++k) wh0[k] = W_hh0[r * 4 + (u ^ k)];   // xor order

        float h0 = 0.f, c0 = 0.f, h0b = 0.f, h0c = 0.f, h0d = 0.f;

        const float* xrow = x + (size_t)batch * T_STEPS * 3;
        // prime: stage chunk 0 into x-slot 0, load chunk 1 into regs
        const float* p0 = xrow + idx * 3;
        xstage[pr][0][ch * 17 + idx] = make_float4(p0[0], p0[1], p0[2], 0.f);
        const float* p1 = xrow + 48 + idx * 3;
        float q0 = p1[0], q1 = p1[1], q2 = p1[2];

        volatile int* ff = &free0[pr][0];

        for (int c = 0; c < NCHUNK; ++c) {
            const int s = c & (RDEPTH - 1);
            // ring credit: previous occupant of slot s was chunk c-RDEPTH
            if (c >= RDEPTH) {
                while (ff[s] < c - RDEPTH + 1) { __builtin_amdgcn_s_sleep(1); }
            }

            // ---- prepass: x-contribution for all 16 steps -> registers ----
            // xg[tt] = fma(wx2,z, fma(wx1,y, fma(wx0,x, bias0)))  (same order as R9)
            const float4* xs = &xstage[pr][c & 1][ch * 17];
            float xg[CHUNK];
#pragma unroll
            for (int tt = 0; tt < CHUNK; ++tt) {
                float4 xv = xs[tt];
                xg[tt] = bias0 + wx0 * xv.x + wx1 * xv.y + wx2 * xv.z;
            }

            // ---- body: pure-register recurrence, h snapshots to hs0[] ----
            float hs0[CHUNK];
#pragma unroll
            for (int tt = 0; tt < CHUNK; ++tt) {
                float pre0 = xg[tt]
                           + wh0[0] * h0 + wh0[1] * h0b + wh0[2] * h0c + wh0[3] * h0d;
                float a0 = aa * fast_rcp(1.0f + fast_exp2(am * pre0)) + ab;
                float gi = dpp_mov<DPP_QB0>(a0);
                float gf = dpp_mov<DPP_QB1>(a0);
                float gg = dpp_mov<DPP_QB2>(a0);
                float go = dpp_mov<DPP_QB3>(a0);
                c0 = gf * c0 + gi * gg;
                h0 = go * fast_tanh(c0);
                h0b = dpp_mov<DPP_HALF_MIRROR>(h0);
                h0c = dpp_mov<DPP_ROR8>(h0);
                h0d = dpp_mov<DPP_MIRROR>(h0);
                hs0[tt] = h0;
            }

            // ---- batched ring writes (one exec-mask set, 16 stores) ----
            if (rho == 0) {
                float* rw = &((float*)&ring0[pr][s][0][ch])[u];   // step stride 16 floats
#pragma unroll
                for (int tt = 0; tt < CHUNK; ++tt) rw[tt * 16] = hs0[tt];
            }
            // publish chunk c
            __threadfence_block();
            if (lane == 0) done0[pr][s] = c + 1;

            // stage chunk c+1 (regs loaded last chunk), prefetch chunk c+2
            if (c < NCHUNK - 1)
                xstage[pr][(c + 1) & 1][ch * 17 + idx] = make_float4(q0, q1, q2, 0.f);
            if (c < NCHUNK - 2) {
                const float* p = xrow + (c + 2) * 48 + idx * 3;
                q0 = p[0]; q1 = p[1]; q2 = p[2];
            }
        }
    } else if (stg == 1) {
        // ==================== stage B: layer 1 (cell only) =======================
        const float bias1 = b_ih1[r] + b_hh1[r];
        float wi1[4], wh1[4];
#pragma unroll
        for (int k = 0; k < 4; ++k) {
            wi1[k] = W_ih1[r * 4 + k];          // PLAIN order (ring h0 is plain)
            wh1[k] = W_hh1[r * 4 + (u ^ k)];    // xor order (register quad)
        }

        float h1 = 0.f, c1 = 0.f, h1b = 0.f, h1c = 0.f, h1d = 0.f;

        volatile int* df = &done0[pr][0];
        volatile int* f1 = &free1[pr][0];

        for (int c = 0; c < NCHUNK; ++c) {
            const int s = c & (RDEPTH - 1);
            while (df[s] < c + 1) { __builtin_amdgcn_s_sleep(1); }
            if (c >= RDEPTH) {
                while (f1[s] < c - RDEPTH + 1) { __builtin_amdgcn_s_sleep(1); }
            }
            __threadfence_block();

            // ---- prepass: ring-h0 contribution for all 16 steps -> registers ----
            // xb[tt] = fma(wi3,w, fma(wi2,z, fma(wi1,y, fma(wi0,x, bias1))))
            const float4* rgp = &ring0[pr][s][0][ch];   // step stride = 4 float4s
            float xb[CHUNK];
#pragma unroll
            for (int tt = 0; tt < CHUNK; ++tt) {
                float4 hv = rgp[tt * 4];
                xb[tt] = bias1 + wi1[0] * hv.x + wi1[1] * hv.y
                               + wi1[2] * hv.z + wi1[3] * hv.w;
            }

            // ---- body: pure-register recurrence, h snapshots to hs1[] ----
            float hs1[CHUNK];
#pragma unroll
            for (int tt = 0; tt < CHUNK; ++tt) {
                float pre1 = xb[tt]
                           + wh1[0] * h1 + wh1[1] * h1b + wh1[2] * h1c + wh1[3] * h1d;
                float a1 = aa * fast_rcp(1.0f + fast_exp2(am * pre1)) + ab;
                float gi1 = dpp_mov<DPP_QB0>(a1);
                float gf1 = dpp_mov<DPP_QB1>(a1);
                float gg1 = dpp_mov<DPP_QB2>(a1);
                float go1 = dpp_mov<DPP_QB3>(a1);
                c1 = gf1 * c1 + gi1 * gg1;
                h1 = go1 * fast_tanh(c1);
                h1b = dpp_mov<DPP_HALF_MIRROR>(h1);
                h1c = dpp_mov<DPP_ROR8>(h1);
                h1d = dpp_mov<DPP_MIRROR>(h1);
                hs1[tt] = h1;
            }

            // ---- batched ring1 writes ----
            if (rho == 0) {
                float* rw = &((float*)&ring1[pr][s][0][ch])[u];
#pragma unroll
                for (int tt = 0; tt < CHUNK; ++tt) rw[tt * 16] = hs1[tt];
            }
            // release ring0 slot (prepass reads all consumed; per-wave LDS in-order),
            // then publish ring1 chunk (fence makes data visible before flag)
            if (lane == 0) free0[pr][s] = c + 1;
            __threadfence_block();
            if (lane == 0) done1[pr][s] = c + 1;
        }
    } else {
        // =================== stage C: MLP head consumer ==========================
        // Zero-redundancy layout: lane = cch*16 + sb*4 + cu handles (chain cch,
        // step it*4+sb, unit cu) -> 4 timesteps per iteration across 64 lanes.
        const int cu  = lane & 3;           // hidden unit
        const int sb  = (lane >> 2) & 3;    // step sub-slot
        const int cch = lane >> 4;          // chain within pair
        const int cbatch = blockIdx.x * 16 + pr * 4 + cch;

        float w1r[4];
#pragma unroll
        for (int k = 0; k < 4; ++k) w1r[k] = W1[cu * 4 + k];   // plain order
        const float b1u = b1[cu];
        const float w2u = W2[cu];
        const float b2v = b2[0];
        float* op = out + (size_t)cbatch * T_STEPS;

        volatile int* d1 = &done1[pr][0];

        for (int c = 0; c < NCHUNK; ++c) {
            const int s = c & (RDEPTH - 1);
            while (d1[s] < c + 1) { __builtin_amdgcn_s_sleep(1); }
            __threadfence_block();

            // lane reads h1[chain cch][t = it*4+sb] as one float4 (quad-broadcast,
            // 2-way bank aliasing = free); it*16 float4s = it*256 B imm offset
            const float4* rg = &ring1[pr][s][sb][cch];
            float yq[4];
#pragma unroll
            for (int it = 0; it < 4; ++it) {
                float4 h = rg[it * 16];
                float zp = b1u + w1r[0] * h.x + w1r[1] * h.y
                               + w1r[2] * h.z + w1r[3] * h.w;
                float z  = fast_tanh(zp);
                float yv = w2u * z;
                // sum over the 4 units of the quad: (u + u^2) + (u^1 + u^3) + b2
                float t1 = yv + dpp_mov<DPP_QSWAP2>(yv);
                yq[it]   = t1 + dpp_mov<DPP_QSWAP1>(t1) + b2v;
            }
            // release ring1 slot (all reads consumed above; values live in yq regs)
            if (lane == 0) free1[pr][s] = c + 1;

            // store: 16 active lanes (cch, sb), 4 consecutive floats per chain per it
            if (cu == 0) {
#pragma unroll
                for (int it = 0; it < 4; ++it)
                    op[c * CHUNK + it * 4 + sb] = yq[it];
            }
        }
    }
}

extern "C" void kernel_launch(void* const* d_in, const int* in_sizes, int n_in,
                              void* d_out, int out_size, void* d_ws, size_t ws_size,
                              hipStream_t stream) {
    const float* x     = (const float*)d_in[0];
    const float* W_ih0 = (const float*)d_in[1];
    const float* W_hh0 = (const float*)d_in[2];
    const float* b_ih0 = (const float*)d_in[3];
    const float* b_hh0 = (const float*)d_in[4];
    const float* W_ih1 = (const float*)d_in[5];
    const float* W_hh1 = (const float*)d_in[6];
    const float* b_ih1 = (const float*)d_in[7];
    const float* b_hh1 = (const float*)d_in[8];
    const float* W1    = (const float*)d_in[9];
    const float* b1    = (const float*)d_in[10];
    const float* W2    = (const float*)d_in[11];
    const float* b2    = (const float*)d_in[12];
    float* out = (float*)d_out;

    dim3 grid(BATCH / 16);   // 256 blocks = 1 per CU, 16 chains each
    dim3 block(768);         // 12 waves; w%4 -> S0: A0,A1,C0 | S1: A2,A3,C1
                             //                 S2: B0,B1,C2 | S3: B2,B3,C3
    lstm_r13_kernel<<<grid, block, 0, stream>>>(
        x, W_ih0, W_hh0, b_ih0, b_hh0, W_ih1, W_hh1, b_ih1, b_hh1,
        W1, b1, W2, b2, out);
}